// Round 1
// baseline (444.066 us; speedup 1.0000x reference)
//
#include <hip/hip_runtime.h>

#define S_LEN 4096
#define I_LEN 1024
#define CC 8
#define HH 8

__device__ __forceinline__ float bf2f(unsigned int lo16) {
  unsigned int u = lo16 << 16;
  float f; __builtin_memcpy(&f, &u, 4); return f;
}
__device__ __forceinline__ unsigned int f2bf(float f) {
  unsigned int u; __builtin_memcpy(&u, &f, 4);
  return (u + 0x7FFFu + ((u >> 16) & 1u)) >> 16;  // RNE
}

// K1: block b handles columns 4b..4b+3. 1024 threads: col = t&3, r = t>>2.
// Each thread owns s = r + 256*j, j=0..15 for its col; k,v (bf16-packed) and
// bias stay in registers across the three passes (no big LDS arrays).
__global__ __launch_bounds__(1024) void msa_k1(
    const float* __restrict__ m, const float* __restrict__ mask,
    const float* __restrict__ lng, const float* __restrict__ lnb,
    const float* __restrict__ Wq, const float* __restrict__ Wk,
    const float* __restrict__ Wv, float* __restrict__ o_tab)
{
  __shared__ float red[16][4][16];   // [wave][col][quantity]
  __shared__ float fin[4][9];        // pooled qn[0..7], qden at [8]
  __shared__ float qtab[4][8];
  __shared__ float mxtab[4][8];

  const int t    = threadIdx.x;
  const int col  = t & 3;
  const int r    = t >> 2;       // 0..255
  const int lane = t & 63;
  const int wave = t >> 6;
  const int icol = blockIdx.x * 4 + col;

  float gam[8], bet[8], wk[8], wv[8];
#pragma unroll
  for (int c = 0; c < 8; ++c) { gam[c]=lng[c]; bet[c]=lnb[c]; wk[c]=Wk[c]; wv[c]=Wv[c]; }

  unsigned int kv[16];
  float bias[16];
  float qn[8] = {0,0,0,0,0,0,0,0};
  float qd = 0.0f;

  // ---- pass 1: LN, k/v, pooled-q partials ----
#pragma unroll
  for (int j = 0; j < 16; ++j) {
    const int s = r + 256 * j;
    const float4* mp = (const float4*)(m + (size_t)(s * I_LEN + icol) * CC);
    float4 lo = mp[0], hi = mp[1];
    float x[8] = {lo.x, lo.y, lo.z, lo.w, hi.x, hi.y, hi.z, hi.w};
    float mu = 0.f;
#pragma unroll
    for (int c = 0; c < 8; ++c) mu += x[c];
    mu *= 0.125f;
    float var = 0.f;
#pragma unroll
    for (int c = 0; c < 8; ++c) { float d = x[c] - mu; var = fmaf(d, d, var); }
    const float rstd = rsqrtf(var * 0.125f + 1e-5f);
    const float mk = mask[s * I_LEN + icol];
    float kk = 0.f, vv = 0.f;
#pragma unroll
    for (int c = 0; c < 8; ++c) {
      float mn = fmaf((x[c] - mu) * rstd, gam[c], bet[c]);
      kk = fmaf(mn, wk[c], kk);
      vv = fmaf(mn, wv[c], vv);
      qn[c] = fmaf(mn, mk, qn[c]);
    }
    qd += mk;
    kv[j] = (f2bf(kk) << 16) | f2bf(vv);
    bias[j] = 1e9f * (mk - 1.0f);
  }

  // ---- reduce pooled q over 256 threads per col ----
#pragma unroll
  for (int q = 0; q < 9; ++q) {
    float x = (q < 8) ? qn[q] : qd;
#pragma unroll
    for (int off = 4; off <= 32; off <<= 1) x += __shfl_xor(x, off, 64);
    if (lane < 4) red[wave][lane][q] = x;
  }
  __syncthreads();
  if (t < 36) {
    int cc = t / 9, q = t - cc * 9;
    float s = 0.f;
#pragma unroll
    for (int w = 0; w < 16; ++w) s += red[w][cc][q];
    fin[cc][q] = s;
  }
  __syncthreads();
  if (t < 32) {
    int cc = t >> 3, h = t & 7;
    float invd = 1.0f / (fin[cc][8] + 1e-5f);
    float qv = 0.f;
#pragma unroll
    for (int c = 0; c < 8; ++c) qv = fmaf(fin[cc][c] * invd, Wq[c * 8 + h], qv);
    qtab[cc][h] = qv;  // * c_h^-0.5 == 1 since c_h==1
  }
  __syncthreads();

  float qh[8];
#pragma unroll
  for (int h = 0; h < 8; ++h) qh[h] = qtab[col][h];

  // ---- pass 2: per-head max logit ----
  float mx[8];
#pragma unroll
  for (int h = 0; h < 8; ++h) mx[h] = -3.0e38f;
#pragma unroll
  for (int j = 0; j < 16; ++j) {
    const float kk = bf2f(kv[j] >> 16);
    const float b  = bias[j];
#pragma unroll
    for (int h = 0; h < 8; ++h) mx[h] = fmaxf(mx[h], fmaf(qh[h], kk, b));
  }
#pragma unroll
  for (int h = 0; h < 8; ++h) {
    float x = mx[h];
#pragma unroll
    for (int off = 4; off <= 32; off <<= 1) x = fmaxf(x, __shfl_xor(x, off, 64));
    if (lane < 4) red[wave][lane][h] = x;
  }
  __syncthreads();
  if (t < 32) {
    int cc = t >> 3, h = t & 7;
    float v = -3.0e38f;
#pragma unroll
    for (int w = 0; w < 16; ++w) v = fmaxf(v, red[w][cc][h]);
    mxtab[cc][h] = v;
  }
  __syncthreads();
#pragma unroll
  for (int h = 0; h < 8; ++h) mx[h] = mxtab[col][h];

  // ---- pass 3: sum exp, sum exp*v ----
  float se[8] = {0,0,0,0,0,0,0,0};
  float sv[8] = {0,0,0,0,0,0,0,0};
#pragma unroll
  for (int j = 0; j < 16; ++j) {
    const float kk = bf2f(kv[j] >> 16);
    const float vv = bf2f(kv[j] & 0xFFFFu);
    const float b  = bias[j];
#pragma unroll
    for (int h = 0; h < 8; ++h) {
      float e = __expf(fmaf(qh[h], kk, b) - mx[h]);
      se[h] += e;
      sv[h] = fmaf(e, vv, sv[h]);
    }
  }
#pragma unroll
  for (int q = 0; q < 16; ++q) {
    float x = (q < 8) ? se[q] : sv[q - 8];
#pragma unroll
    for (int off = 4; off <= 32; off <<= 1) x += __shfl_xor(x, off, 64);
    if (lane < 4) red[wave][lane][q] = x;
  }
  __syncthreads();
  if (t < 32) {
    int cc = t >> 3, h = t & 7;
    float a = 0.f, b = 0.f;
#pragma unroll
    for (int w = 0; w < 16; ++w) { a += red[w][cc][h]; b += red[w][cc][8 + h]; }
    o_tab[(blockIdx.x * 4 + cc) * 8 + h] = b / a;
  }
}

// K2: streaming pass. One (s,i) pair per thread-iteration, fully coalesced.
// Weights live in registers (folded: GW = gamma*Wg so LN mul folds into the dot).
__global__ __launch_bounds__(256) void msa_k2(
    const float* __restrict__ m,
    const float* __restrict__ lng, const float* __restrict__ lnb,
    const float* __restrict__ Wg, const float* __restrict__ bg,
    const float* __restrict__ Wo, const float* __restrict__ bo,
    const float* __restrict__ o_tab, float* __restrict__ out)
{
  float GW[64], sg[8], tb[8], wo[64], bov[8];
#pragma unroll
  for (int h = 0; h < 8; ++h) { sg[h] = 0.f; tb[h] = bg[h]; }
#pragma unroll
  for (int c = 0; c < 8; ++c) {
    const float ga = lng[c], be = lnb[c];
#pragma unroll
    for (int h = 0; h < 8; ++h) {
      const float w = Wg[c * 8 + h];
      GW[c * 8 + h] = ga * w;
      sg[h] += ga * w;
      tb[h] = fmaf(be, w, tb[h]);
    }
  }
#pragma unroll
  for (int k = 0; k < 64; ++k) wo[k] = Wo[k];
#pragma unroll
  for (int c = 0; c < 8; ++c) bov[c] = bo[c];

  const int tid = blockIdx.x * 256 + threadIdx.x;   // 524288 threads total
#pragma unroll 2
  for (int jj = 0; jj < 8; ++jj) {
    const int p = tid + jj * 524288;                // p = s*1024 + i
    const float4* mp = (const float4*)(m + (size_t)p * 8);
    float4 lo = mp[0], hi = mp[1];
    float x[8] = {lo.x, lo.y, lo.z, lo.w, hi.x, hi.y, hi.z, hi.w};
    const int i = p & (I_LEN - 1);
    const float4* op = (const float4*)(o_tab + i * 8);
    float4 o1 = op[0], o2 = op[1];
    float A[8] = {o1.x, o1.y, o1.z, o1.w, o2.x, o2.y, o2.z, o2.w};
    float su = 0.f, s2 = 0.f;
#pragma unroll
    for (int c = 0; c < 8; ++c) { su += x[c]; s2 = fmaf(x[c], x[c], s2); }
    const float mu = su * 0.125f;
    const float var = s2 * 0.125f - mu * mu;
    const float rstd = rsqrtf(var + 1e-5f);
    float acc[8];
#pragma unroll
    for (int c = 0; c < 8; ++c) acc[c] = bov[c];
#pragma unroll
    for (int h = 0; h < 8; ++h) {
      float d = 0.f;
#pragma unroll
      for (int c = 0; c < 8; ++c) d = fmaf(x[c], GW[c * 8 + h], d);
      const float gl = fmaf(rstd, d - mu * sg[h], tb[h]);   // = mn@Wg[:,h]+bg[h]
      const float gv = 1.0f / (1.0f + __expf(-gl));
      const float w = A[h] * gv;
#pragma unroll
      for (int c = 0; c < 8; ++c) acc[c] = fmaf(w, wo[h * 8 + c], acc[c]);
    }
    float4 r0 = make_float4(acc[0], acc[1], acc[2], acc[3]);
    float4 r1 = make_float4(acc[4], acc[5], acc[6], acc[7]);
    float4* outp = (float4*)(out + (size_t)p * 8);
    outp[0] = r0; outp[1] = r1;
  }
}

extern "C" void kernel_launch(void* const* d_in, const int* in_sizes, int n_in,
                              void* d_out, int out_size, void* d_ws, size_t ws_size,
                              hipStream_t stream) {
  const float* m    = (const float*)d_in[0];
  const float* mask = (const float*)d_in[1];
  const float* lng  = (const float*)d_in[2];
  const float* lnb  = (const float*)d_in[3];
  const float* Wq   = (const float*)d_in[4];
  const float* Wk   = (const float*)d_in[5];
  const float* Wv   = (const float*)d_in[6];
  const float* Wg   = (const float*)d_in[7];
  const float* bg   = (const float*)d_in[8];
  const float* Wo   = (const float*)d_in[9];
  const float* bo   = (const float*)d_in[10];
  float* out   = (float*)d_out;
  float* o_tab = (float*)d_ws;   // 1024*8 floats = 32 KB

  hipLaunchKernelGGL(msa_k1, dim3(256), dim3(1024), 0, stream,
                     m, mask, lng, lnb, Wq, Wk, Wv, o_tab);
  hipLaunchKernelGGL(msa_k2, dim3(2048), dim3(256), 0, stream,
                     m, lng, lnb, Wg, bg, Wo, bo, o_tab, out);
}

// Round 2
// 443.330 us; speedup vs baseline: 1.0017x; 1.0017x over previous
//
#include <hip/hip_runtime.h>

#define I_LEN 1024

__device__ __forceinline__ float bf2f(unsigned int lo16) {
  unsigned int u = lo16 << 16;
  float f; __builtin_memcpy(&f, &u, 4); return f;
}
__device__ __forceinline__ unsigned int f2bf(float f) {
  unsigned int u; __builtin_memcpy(&u, &f, 4);
  return (u + 0x7FFFu + ((u >> 16) & 1u)) >> 16;  // RNE
}

// K1: block b handles columns 4b..4b+3. 1024 threads: col = t&3, r = t>>2.
// Two passes, no softmax-max pass (logits are O(1), exp is safe; masked
// entries multiply by 0 which matches bias=-1e9 exactly for binary masks).
// Register budget: launch_bounds(1024,4) -> 128 VGPR cap; live state ~80.
__global__ __launch_bounds__(1024, 4) void msa_k1(
    const float* __restrict__ m, const float* __restrict__ mask,
    const float* __restrict__ lng, const float* __restrict__ lnb,
    const float* __restrict__ Wq, const float* __restrict__ Wk,
    const float* __restrict__ Wv, float* __restrict__ o_tab)
{
  __shared__ float red[16][4][16];   // [wave][col][quantity]
  __shared__ float fin[4][9];        // reduced sum(xhat*mk)[0..7], sum(mk) at [8]
  __shared__ float qtab[4][8];

  const int t    = threadIdx.x;
  const int col  = t & 3;
  const int r    = t >> 2;       // 0..255
  const int lane = t & 63;
  const int wave = t >> 6;
  const int icol = blockIdx.x * 4 + col;

  // gamma folded into Wk/Wv; beta contributes a constant to k,v.
  float wkg[8], wvg[8];
  float swk = 0.f, swv = 0.f, kb = 0.f, vb = 0.f;
#pragma unroll
  for (int c = 0; c < 8; ++c) {
    const float ga = lng[c], be = lnb[c], k0 = Wk[c], v0 = Wv[c];
    wkg[c] = ga * k0; wvg[c] = ga * v0;
    swk += wkg[c];    swv += wvg[c];
    kb = fmaf(be, k0, kb); vb = fmaf(be, v0, vb);
  }

  unsigned int kv[16];
  unsigned int mb = 0;             // 16 mask bits
  float qnx[8] = {0,0,0,0,0,0,0,0};  // sum over s of xhat_c * mk
  float qd = 0.0f;                   // sum over s of mk

  // ---- pass 1: LN stats, k/v (packed bf16), pooled-q partials ----
#pragma unroll
  for (int j = 0; j < 16; ++j) {
    const int s = r + 256 * j;
    const float4* mp = (const float4*)(m + (size_t)(s * I_LEN + icol) * 8);
    float4 lo = mp[0], hi = mp[1];
    float x[8] = {lo.x, lo.y, lo.z, lo.w, hi.x, hi.y, hi.z, hi.w};
    float su = 0.f;
#pragma unroll
    for (int c = 0; c < 8; ++c) su += x[c];
    const float mu = su * 0.125f;
    float var = 0.f;
#pragma unroll
    for (int c = 0; c < 8; ++c) { float d = x[c] - mu; var = fmaf(d, d, var); }
    const float rstd = rsqrtf(var * 0.125f + 1e-5f);
    const float mk = mask[s * I_LEN + icol];
    float dk = 0.f, dv = 0.f;
#pragma unroll
    for (int c = 0; c < 8; ++c) { dk = fmaf(x[c], wkg[c], dk); dv = fmaf(x[c], wvg[c], dv); }
    const float kk = fmaf(rstd, dk - mu * swk, kb);
    const float vv = fmaf(rstd, dv - mu * swv, vb);
    const float mr = mk * rstd;
#pragma unroll
    for (int c = 0; c < 8; ++c) qnx[c] = fmaf(x[c] - mu, mr, qnx[c]);
    qd += mk;
    kv[j] = (f2bf(kk) << 16) | f2bf(vv);
    mb |= (mk > 0.5f ? 1u : 0u) << j;
  }

  // ---- reduce pooled-q partials over the 256 threads of each col ----
#pragma unroll
  for (int q = 0; q < 9; ++q) {
    float x = (q < 8) ? qnx[q] : qd;
#pragma unroll
    for (int off = 4; off <= 32; off <<= 1) x += __shfl_xor(x, off, 64);
    if (lane < 4) red[wave][lane][q] = x;
  }
  __syncthreads();
  if (t < 36) {
    int cc = t / 9, q = t - cc * 9;
    float s = 0.f;
#pragma unroll
    for (int w = 0; w < 16; ++w) s += red[w][cc][q];
    fin[cc][q] = s;
  }
  __syncthreads();
  if (t < 32) {
    int cc = t >> 3, h = t & 7;
    const float invd = 1.0f / (fin[cc][8] + 1e-5f);
    float qv = 0.f;
#pragma unroll
    for (int c = 0; c < 8; ++c) {
      // qn_c = gamma_c * sum(xhat*mk) + beta_c * sum(mk)
      const float qn = fmaf(lng[c], fin[cc][c], lnb[c] * fin[cc][8]);
      qv = fmaf(qn * invd, Wq[c * 8 + h], qv);   // c_h^-0.5 == 1
    }
    qtab[cc][h] = qv;
  }
  __syncthreads();

  float qh[8];
#pragma unroll
  for (int h = 0; h < 8; ++h) qh[h] = qtab[col][h];

  // ---- pass 2: sum exp, sum exp*v (no max-subtraction needed) ----
  float se[8] = {0,0,0,0,0,0,0,0};
  float sv[8] = {0,0,0,0,0,0,0,0};
#pragma unroll
  for (int j = 0; j < 16; ++j) {
    const float kk = bf2f(kv[j] >> 16);
    const float vv = bf2f(kv[j] & 0xFFFFu);
    const float on = ((mb >> j) & 1u) ? 1.0f : 0.0f;
#pragma unroll
    for (int h = 0; h < 8; ++h) {
      const float e = __expf(qh[h] * kk) * on;
      se[h] += e;
      sv[h] = fmaf(e, vv, sv[h]);
    }
  }
#pragma unroll
  for (int q = 0; q < 16; ++q) {
    float x = (q < 8) ? se[q] : sv[q - 8];
#pragma unroll
    for (int off = 4; off <= 32; off <<= 1) x += __shfl_xor(x, off, 64);
    if (lane < 4) red[wave][lane][q] = x;
  }
  __syncthreads();
  if (t < 32) {
    int cc = t >> 3, h = t & 7;
    float a = 0.f, b = 0.f;
#pragma unroll
    for (int w = 0; w < 16; ++w) { a += red[w][cc][h]; b += red[w][cc][8 + h]; }
    o_tab[(blockIdx.x * 4 + cc) * 8 + h] = b / a;
  }
}

// K2: streaming pass, 4 points per thread (strided by 1M -> same column i,
// so one o_tab load). launch_bounds(256,1) -> 512 VGPR cap, weights resident.
__global__ __launch_bounds__(256, 1) void msa_k2(
    const float* __restrict__ m,
    const float* __restrict__ lng, const float* __restrict__ lnb,
    const float* __restrict__ Wg, const float* __restrict__ bg,
    const float* __restrict__ Wo, const float* __restrict__ bo,
    const float* __restrict__ o_tab, float* __restrict__ out)
{
  float GW[64], sg[8], tb[8], wo[64], bov[8];
#pragma unroll
  for (int h = 0; h < 8; ++h) { sg[h] = 0.f; tb[h] = bg[h]; }
#pragma unroll
  for (int c = 0; c < 8; ++c) {
    const float ga = lng[c], be = lnb[c];
#pragma unroll
    for (int h = 0; h < 8; ++h) {
      const float w = Wg[c * 8 + h];
      GW[c * 8 + h] = ga * w;
      sg[h] += ga * w;
      tb[h] = fmaf(be, w, tb[h]);
    }
  }
#pragma unroll
  for (int k = 0; k < 64; ++k) wo[k] = Wo[k];
#pragma unroll
  for (int c = 0; c < 8; ++c) bov[c] = bo[c];

  const int tid = blockIdx.x * 256 + threadIdx.x;   // 1,048,576 threads
  const int i = tid & (I_LEN - 1);                  // same for all 4 points

  // issue all global loads up-front for MLP
  float4 L[8];
#pragma unroll
  for (int q = 0; q < 4; ++q) {
    const float4* mp = (const float4*)(m + (size_t)(tid + q * 1048576) * 8);
    L[2 * q]     = mp[0];
    L[2 * q + 1] = mp[1];
  }
  const float4* op = (const float4*)(o_tab + i * 8);
  const float4 o1 = op[0], o2 = op[1];
  const float A[8] = {o1.x, o1.y, o1.z, o1.w, o2.x, o2.y, o2.z, o2.w};

#pragma unroll
  for (int q = 0; q < 4; ++q) {
    const float4 lo = L[2 * q], hi = L[2 * q + 1];
    float x[8] = {lo.x, lo.y, lo.z, lo.w, hi.x, hi.y, hi.z, hi.w};
    float su = 0.f, s2 = 0.f;
#pragma unroll
    for (int c = 0; c < 8; ++c) { su += x[c]; s2 = fmaf(x[c], x[c], s2); }
    const float mu = su * 0.125f;
    const float var = s2 * 0.125f - mu * mu;
    const float rstd = rsqrtf(var + 1e-5f);
    float acc[8];
#pragma unroll
    for (int c = 0; c < 8; ++c) acc[c] = bov[c];
#pragma unroll
    for (int h = 0; h < 8; ++h) {
      float d = 0.f;
#pragma unroll
      for (int c = 0; c < 8; ++c) d = fmaf(x[c], GW[c * 8 + h], d);
      const float gl = fmaf(rstd, d - mu * sg[h], tb[h]);   // mn@Wg[:,h]+bg[h]
      const float gv = 1.0f / (1.0f + __expf(-gl));
      const float w = A[h] * gv;
#pragma unroll
      for (int c = 0; c < 8; ++c) acc[c] = fmaf(w, wo[h * 8 + c], acc[c]);
    }
    float4* outp = (float4*)(out + (size_t)(tid + q * 1048576) * 8);
    outp[0] = make_float4(acc[0], acc[1], acc[2], acc[3]);
    outp[1] = make_float4(acc[4], acc[5], acc[6], acc[7]);
  }
}

extern "C" void kernel_launch(void* const* d_in, const int* in_sizes, int n_in,
                              void* d_out, int out_size, void* d_ws, size_t ws_size,
                              hipStream_t stream) {
  const float* m    = (const float*)d_in[0];
  const float* mask = (const float*)d_in[1];
  const float* lng  = (const float*)d_in[2];
  const float* lnb  = (const float*)d_in[3];
  const float* Wq   = (const float*)d_in[4];
  const float* Wk   = (const float*)d_in[5];
  const float* Wv   = (const float*)d_in[6];
  const float* Wg   = (const float*)d_in[7];
  const float* bg   = (const float*)d_in[8];
  const float* Wo   = (const float*)d_in[9];
  const float* bo   = (const float*)d_in[10];
  float* out   = (float*)d_out;
  float* o_tab = (float*)d_ws;   // 1024*8 floats = 32 KB

  hipLaunchKernelGGL(msa_k1, dim3(256), dim3(1024), 0, stream,
                     m, mask, lng, lnb, Wq, Wk, Wv, o_tab);
  hipLaunchKernelGGL(msa_k2, dim3(4096), dim3(256), 0, stream,
                     m, lng, lnb, Wg, bg, Wo, bo, o_tab, out);
}

// Round 3
// 307.746 us; speedup vs baseline: 1.4430x; 1.4406x over previous
//
#include <hip/hip_runtime.h>

#define I_LEN 1024

__device__ __forceinline__ float bf2f(unsigned int lo16) {
  unsigned int u = lo16 << 16;
  float f; __builtin_memcpy(&f, &u, 4); return f;
}
__device__ __forceinline__ unsigned int f2bf(float f) {
  unsigned int u; __builtin_memcpy(&u, &f, 4);
  return (u + 0x7FFFu + ((u >> 16) & 1u)) >> 16;  // RNE
}

// K1: block b handles columns 4b..4b+3. 1024 threads: col = t&3, r = t>>2.
// k/v live in LDS (not registers); weights stay raw in SGPRs (uniform s_loads);
// mask is a 16-bit register word. Live VGPRs ~50 -> fits the 64-VGPR target the
// allocator pins for 1024-thread blocks (R1/R2 spilled ~500MB to scratch).
__global__ __launch_bounds__(1024) void msa_k1(
    const float* __restrict__ m, const float* __restrict__ mask,
    const float* __restrict__ lng, const float* __restrict__ lnb,
    const float* __restrict__ Wq, const float* __restrict__ Wk,
    const float* __restrict__ Wv, float* __restrict__ o_tab)
{
  __shared__ unsigned int kvs[4096 * 4];   // 64 KB, idx = s*4+col (bank-friendly)
  __shared__ float red[16][4][16];         // [wave][col][quantity]
  __shared__ float fin[4][9];
  __shared__ float qtab[4][8];

  const int t    = threadIdx.x;
  const int col  = t & 3;
  const int r    = t >> 2;       // 0..255
  const int lane = t & 63;
  const int wave = t >> 6;
  const int icol = blockIdx.x * 4 + col;

  // uniform scalars (VALU on SGPR-loaded values -> 4 uniform VGPRs)
  float swk = 0.f, swv = 0.f, kb = 0.f, vb = 0.f;
#pragma unroll
  for (int c = 0; c < 8; ++c) {
    swk = fmaf(lng[c], Wk[c], swk);  swv = fmaf(lng[c], Wv[c], swv);
    kb  = fmaf(lnb[c], Wk[c], kb);   vb  = fmaf(lnb[c], Wv[c], vb);
  }

  unsigned int mb = 0;               // 16 mask bits (register)
  float qnx[8] = {0,0,0,0,0,0,0,0};  // sum over s of (gamma*xhat)_c * mk
  float qd = 0.0f;                   // sum over s of mk

  // ---- pass 1: LN, k/v -> LDS, pooled-q partials ----
#pragma unroll 2
  for (int j = 0; j < 16; ++j) {
    const int s = r + 256 * j;
    const float4* mp = (const float4*)(m + (size_t)(s * I_LEN + icol) * 8);
    float4 lo = mp[0], hi = mp[1];
    const float mk = mask[s * I_LEN + icol];
    float x[8] = {lo.x, lo.y, lo.z, lo.w, hi.x, hi.y, hi.z, hi.w};
    float su = 0.f, s2 = 0.f;
#pragma unroll
    for (int c = 0; c < 8; ++c) { su += x[c]; s2 = fmaf(x[c], x[c], s2); }
    const float mu   = su * 0.125f;
    const float var  = s2 * 0.125f - mu * mu;
    const float rstd = rsqrtf(var + 1e-5f);
    float dk = 0.f, dv = 0.f;
#pragma unroll
    for (int c = 0; c < 8; ++c) {
      const float xg = x[c] * lng[c];       // gamma fold (SGPR mult)
      dk = fmaf(xg, Wk[c], dk);
      dv = fmaf(xg, Wv[c], dv);
      x[c] = xg;
    }
    const float kk  = fmaf(rstd, fmaf(-mu, swk, dk), kb);
    const float vv  = fmaf(rstd, fmaf(-mu, swv, dv), vb);
    const float mr  = mk * rstd;
    const float mmr = -mu * mr;
#pragma unroll
    for (int c = 0; c < 8; ++c)
      qnx[c] = fmaf(x[c], mr, fmaf(lng[c], mmr, qnx[c]));
    qd += mk;
    kvs[s * 4 + col] = (f2bf(kk) << 16) | f2bf(vv);
    mb |= (mk > 0.5f ? 1u : 0u) << j;
  }

  // ---- reduce pooled-q partials over the 256 threads of each col ----
#pragma unroll
  for (int q = 0; q < 9; ++q) {
    float x = (q < 8) ? qnx[q] : qd;
#pragma unroll
    for (int off = 4; off <= 32; off <<= 1) x += __shfl_xor(x, off, 64);
    if (lane < 4) red[wave][lane][q] = x;
  }
  __syncthreads();
  if (t < 36) {
    int cc = t / 9, q = t - cc * 9;
    float s = 0.f;
#pragma unroll
    for (int w = 0; w < 16; ++w) s += red[w][cc][q];
    fin[cc][q] = s;
  }
  __syncthreads();
  if (t < 32) {
    int cc = t >> 3, h = t & 7;
    const float invd = 1.0f / (fin[cc][8] + 1e-5f);
    float qv = 0.f;
#pragma unroll
    for (int c = 0; c < 8; ++c) {
      const float qn = fmaf(lnb[c], fin[cc][8], fin[cc][c]);  // + beta*sum(mk)
      qv = fmaf(qn * invd, Wq[c * 8 + h], qv);   // c_h^-0.5 == 1
    }
    qtab[cc][h] = qv;
  }
  __syncthreads();

  float qh[8];
#pragma unroll
  for (int h = 0; h < 8; ++h) qh[h] = qtab[col][h];

  // ---- pass 2: sum exp, sum exp*v (logits O(1): no max-subtraction) ----
  float se[8] = {0,0,0,0,0,0,0,0};
  float sv[8] = {0,0,0,0,0,0,0,0};
#pragma unroll 4
  for (int j = 0; j < 16; ++j) {
    const unsigned int w = kvs[(r + 256 * j) * 4 + col];
    const float kk = bf2f(w >> 16);
    const float vv = bf2f(w & 0xFFFFu);
    const float on = ((mb >> j) & 1u) ? 1.0f : 0.0f;
#pragma unroll
    for (int h = 0; h < 8; ++h) {
      const float e = __expf(qh[h] * kk) * on;
      se[h] += e;
      sv[h] = fmaf(e, vv, sv[h]);
    }
  }
#pragma unroll
  for (int q = 0; q < 16; ++q) {
    float x = (q < 8) ? se[q] : sv[q - 8];
#pragma unroll
    for (int off = 4; off <= 32; off <<= 1) x += __shfl_xor(x, off, 64);
    if (lane < 4) red[wave][lane][q] = x;
  }
  __syncthreads();
  if (t < 32) {
    int cc = t >> 3, h = t & 7;
    float a = 0.f, b = 0.f;
#pragma unroll
    for (int w = 0; w < 16; ++w) { a += red[w][cc][h]; b += red[w][cc][8 + h]; }
    o_tab[(blockIdx.x * 4 + cc) * 8 + h] = b / a;
  }
}

// K2: streaming pass, 8 points/thread strided by 512K (same column i -> one
// o_tab load). Weights are NOT kept in per-thread arrays: raw Wg/Wo reads with
// constant indices are uniform -> s_load -> SGPR operands (no VGPR cost).
__global__ __launch_bounds__(256, 2) void msa_k2(
    const float* __restrict__ m,
    const float* __restrict__ lng, const float* __restrict__ lnb,
    const float* __restrict__ Wg, const float* __restrict__ bg,
    const float* __restrict__ Wo, const float* __restrict__ bo,
    const float* __restrict__ o_tab, float* __restrict__ out)
{
  const int tid = blockIdx.x * 256 + threadIdx.x;   // 524288 threads
  const int i = tid & (I_LEN - 1);                  // same for all 8 points

  // uniform derived vectors (24 uniform VGPRs)
  float sgv[8], tbv[8];
#pragma unroll
  for (int h = 0; h < 8; ++h) {
    float s = 0.f, tb = bg[h];
#pragma unroll
    for (int c = 0; c < 8; ++c) {
      s  = fmaf(lng[c], Wg[c * 8 + h], s);
      tb = fmaf(lnb[c], Wg[c * 8 + h], tb);
    }
    sgv[h] = s; tbv[h] = tb;
  }

  const float4* op = (const float4*)(o_tab + i * 8);
  const float4 o1 = op[0], o2 = op[1];
  const float A[8] = {o1.x, o1.y, o1.z, o1.w, o2.x, o2.y, o2.z, o2.w};

#pragma unroll 2
  for (int q = 0; q < 8; ++q) {
    const size_t p = (size_t)tid + (size_t)q * 524288;
    const float4* mp = (const float4*)(m + p * 8);
    const float4 lo = mp[0], hi = mp[1];
    float x[8] = {lo.x, lo.y, lo.z, lo.w, hi.x, hi.y, hi.z, hi.w};
    float su = 0.f, s2 = 0.f;
#pragma unroll
    for (int c = 0; c < 8; ++c) { su += x[c]; s2 = fmaf(x[c], x[c], s2); }
    const float mu   = su * 0.125f;
    const float var  = s2 * 0.125f - mu * mu;
    const float rstd = rsqrtf(var + 1e-5f);
#pragma unroll
    for (int c = 0; c < 8; ++c) x[c] *= lng[c];     // gamma fold (SGPR mult)
    float acc[8];
#pragma unroll
    for (int c = 0; c < 8; ++c) acc[c] = bo[c];     // SGPR broadcast
#pragma unroll
    for (int h = 0; h < 8; ++h) {
      float d = 0.f;
#pragma unroll
      for (int c = 0; c < 8; ++c) d = fmaf(x[c], Wg[c * 8 + h], d);  // SGPR wgt
      const float gl = fmaf(rstd, fmaf(-mu, sgv[h], d), tbv[h]);
      const float gv = A[h] / (1.0f + __expf(-gl));
#pragma unroll
      for (int c = 0; c < 8; ++c) acc[c] = fmaf(gv, Wo[h * 8 + c], acc[c]);
    }
    float4* outp = (float4*)(out + p * 8);
    outp[0] = make_float4(acc[0], acc[1], acc[2], acc[3]);
    outp[1] = make_float4(acc[4], acc[5], acc[6], acc[7]);
  }
}

extern "C" void kernel_launch(void* const* d_in, const int* in_sizes, int n_in,
                              void* d_out, int out_size, void* d_ws, size_t ws_size,
                              hipStream_t stream) {
  const float* m    = (const float*)d_in[0];
  const float* mask = (const float*)d_in[1];
  const float* lng  = (const float*)d_in[2];
  const float* lnb  = (const float*)d_in[3];
  const float* Wq   = (const float*)d_in[4];
  const float* Wk   = (const float*)d_in[5];
  const float* Wv   = (const float*)d_in[6];
  const float* Wg   = (const float*)d_in[7];
  const float* bg   = (const float*)d_in[8];
  const float* Wo   = (const float*)d_in[9];
  const float* bo   = (const float*)d_in[10];
  float* out   = (float*)d_out;
  float* o_tab = (float*)d_ws;   // 1024*8 floats = 32 KB

  hipLaunchKernelGGL(msa_k1, dim3(256), dim3(1024), 0, stream,
                     m, mask, lng, lnb, Wq, Wk, Wv, o_tab);
  hipLaunchKernelGGL(msa_k2, dim3(2048), dim3(256), 0, stream,
                     m, lng, lnb, Wg, bg, Wo, bo, o_tab, out);
}